// Round 8
// baseline (657.301 us; speedup 1.0000x reference)
//
#include <hip/hip_runtime.h>
#include <hip/hip_bf16.h>

// DIMKT: B=1024, S=200, D=128.
// R8: 1024-thread scan (16 waves = 4/SIMD, split-row epilogue pairs) to hide
// the ~2400cy/step of un-hidden latency seen at 2 waves/SIMD. Wp1s/Wp2s in
// LDS to fit 128 VGPR; Ws1/Ws2/Wkh in regs; sigtanh (3-trans); halved
// shuffle-dot (2 rows/lane); distance-1 pointer-walk streams; lgkm barriers.

#define S_LEN 200
#define NBATCH 1024
#define DIM 128
#define LOG2E 1.4426950408889634f

typedef short short8 __attribute__((ext_vector_type(8)));
typedef float f32x4 __attribute__((ext_vector_type(4)));

__device__ __forceinline__ unsigned short f2b(float f) {
  union { float f; unsigned u; } v; v.f = f;
  unsigned r = (v.u + 0x7FFFu + ((v.u >> 16) & 1u)) >> 16;  // RNE
  return (unsigned short)r;
}
__device__ __forceinline__ float b2f(unsigned short b) {
  union { unsigned u; float f; } v; v.u = ((unsigned)b) << 16;
  return v.f;
}
__device__ __forceinline__ unsigned pk_bf16(float lo, float hi) {
  __hip_bfloat162 t = __float22bfloat162_rn(make_float2(lo, hi));
  union { __hip_bfloat162 h; unsigned u; } cv; cv.h = t;
  return cv.u;
}
// sig(a)*tanh(b) with 3 transcendentals; clamps prevent overflow.
__device__ __forceinline__ float sigtanh(float a, float b) {
  a = fminf(a, 30.0f);
  b = fminf(b, 15.0f);
  const float u = __builtin_amdgcn_exp2f(LOG2E * a);
  const float v = __builtin_amdgcn_exp2f(2.0f * LOG2E * b);
  return (u * (v - 1.0f)) * __builtin_amdgcn_rcpf((1.0f + u) * (v + 1.0f));
}
__device__ __forceinline__ float fast_sigmoid(float x) {
  x = fmaxf(x, -30.0f);
  return __builtin_amdgcn_rcpf(1.0f + __builtin_amdgcn_exp2f(-LOG2E * x));
}
// LDS-only barrier: does NOT drain vmcnt, prefetches stay in flight.
__device__ __forceinline__ void wg_barrier_lds() {
  __asm__ volatile("s_waitcnt lgkmcnt(0)\n\ts_barrier" ::: "memory");
}

// ---------------- P1: projected embedding tables via MFMA, 64 rows/block.
__global__ void proj_all_kernel(const float* __restrict__ Eq, const float* __restrict__ Ec,
                                const float* __restrict__ Eqd, const float* __restrict__ Ecd,
                                const float* __restrict__ Ecorr,
                                const float* __restrict__ Wx,
                                const float* __restrict__ Wp1, const float* __restrict__ bp1,
                                const float* __restrict__ Wp2, const float* __restrict__ bp2,
                                const float* __restrict__ Wk, const float* __restrict__ bk,
                                unsigned short* __restrict__ Tq, unsigned short* __restrict__ Tc,
                                unsigned short* __restrict__ Tqd, unsigned short* __restrict__ Tcd,
                                unsigned short* __restrict__ Tkqd, unsigned short* __restrict__ Tkcd,
                                float* __restrict__ Tkc, float* __restrict__ Tp1c,
                                float* __restrict__ Tp2c) {
  const int bid = blockIdx.x;
  const int tid = threadIdx.x;
  if (bid >= 802) {
    const int blk = bid - 802;
    if (blk < 101) {
      const int o = tid & 127, half = tid >> 7;
      const float* e = (half ? Ecd : Eqd) + (size_t)blk * DIM;
      const float* wr = Wk + (size_t)o * 512 + (half ? 384 : 256);
      float a = 0.f;
      for (int k = 0; k < DIM; ++k) a = fmaf(e[k], wr[k], a);
      (half ? Tkcd : Tkqd)[blk * DIM + o] = f2b(a);
    } else {
      for (int idx = tid; idx < 768; idx += 256) {
        const int t = idx >> 8, e = (idx >> 7) & 1, o = idx & 127;
        const float* ec = Ecorr + e * DIM;
        const float* wr; float bias; float* dst;
        if (t == 0)      { wr = Wp1 + (size_t)o * 256 + 128; bias = bp1[o]; dst = Tp1c; }
        else if (t == 1) { wr = Wp2 + (size_t)o * 256 + 128; bias = bp2[o]; dst = Tp2c; }
        else             { wr = Wk  + (size_t)o * 512 + 128; bias = bk[o];  dst = Tkc;  }
        float a = bias;
        for (int k = 0; k < DIM; ++k) a = fmaf(ec[k], wr[k], a);
        dst[e * DIM + o] = a;
      }
    }
    return;
  }
  const float* E; int M, coff, r0; unsigned short* T;
  if (bid < 782)      { E = Eq;  M = 50000; coff = 0;   T = Tq;  r0 = bid * 64; }
  else if (bid < 798) { E = Ec;  M = 1000;  coff = 128; T = Tc;  r0 = (bid - 782) * 64; }
  else if (bid < 800) { E = Eqd; M = 101;   coff = 256; T = Tqd; r0 = (bid - 798) * 64; }
  else                { E = Ecd; M = 101;   coff = 384; T = Tcd; r0 = (bid - 800) * 64; }

  __shared__ __align__(16) unsigned short A[64][136];
  {
    const int row = tid >> 2, cb = (tid & 3) * 32;
    union U8 { uint4 v; unsigned short s[8]; } o;
#pragma unroll
    for (int cc = 0; cc < 4; ++cc) {
      const int c8 = cb + cc * 8;
      if (r0 + row < M) {
        const float4 e0 = *(const float4*)(E + (size_t)(r0 + row) * DIM + c8);
        const float4 e1 = *(const float4*)(E + (size_t)(r0 + row) * DIM + c8 + 4);
        o.s[0] = f2b(e0.x); o.s[1] = f2b(e0.y); o.s[2] = f2b(e0.z); o.s[3] = f2b(e0.w);
        o.s[4] = f2b(e1.x); o.s[5] = f2b(e1.y); o.s[6] = f2b(e1.z); o.s[7] = f2b(e1.w);
      } else {
        o.v = make_uint4(0, 0, 0, 0);
      }
      *(uint4*)&A[row][c8] = o.v;
    }
  }
  __syncthreads();
  const int w = tid >> 6, L = tid & 63, q = L >> 4, m = L & 15;
  short8 bf[2][4];
#pragma unroll
  for (int T2 = 0; T2 < 2; ++T2) {
    const int n = 32 * w + 16 * T2 + m;
#pragma unroll
    for (int kb = 0; kb < 4; ++kb) {
      const float* src = Wx + (size_t)n * 512 + coff + kb * 32 + q * 8;
      const float4 v0 = *(const float4*)src;
      const float4 v1 = *(const float4*)(src + 4);
      short8 f;
      f[0] = (short)f2b(v0.x); f[1] = (short)f2b(v0.y);
      f[2] = (short)f2b(v0.z); f[3] = (short)f2b(v0.w);
      f[4] = (short)f2b(v1.x); f[5] = (short)f2b(v1.y);
      f[6] = (short)f2b(v1.z); f[7] = (short)f2b(v1.w);
      bf[T2][kb] = f;
    }
  }
  const f32x4 vzero = {0.f, 0.f, 0.f, 0.f};
#pragma unroll
  for (int mt = 0; mt < 4; ++mt) {
    short8 af[4];
#pragma unroll
    for (int kb = 0; kb < 4; ++kb) af[kb] = *(const short8*)&A[mt * 16 + m][kb * 32 + q * 8];
    f32x4 acc[2] = {vzero, vzero};
#pragma unroll
    for (int kb = 0; kb < 4; ++kb) {
#pragma unroll
      for (int T2 = 0; T2 < 2; ++T2)
        acc[T2] = __builtin_amdgcn_mfma_f32_16x16x32_bf16(af[kb], bf[T2][kb], acc[T2], 0, 0, 0);
    }
#pragma unroll
    for (int T2 = 0; T2 < 2; ++T2) {
      const int col = 32 * w + 16 * T2 + m;
#pragma unroll
      for (int i = 0; i < 4; ++i) {
        const int r = r0 + mt * 16 + q * 4 + i;
        if (r < M) T[(size_t)r * DIM + col] = f2b(acc[T2][i]);
      }
    }
  }
}

// ---------------- P2: x[s][b][:] = Tq+Tc+Tqd+Tcd+bx (bf16), corrf.
__global__ void build_x_kernel(const int* __restrict__ qs, const int* __restrict__ cs,
                               const int* __restrict__ qds, const int* __restrict__ cds,
                               const int* __restrict__ corr,
                               const unsigned short* __restrict__ Tq, const unsigned short* __restrict__ Tc,
                               const unsigned short* __restrict__ Tqd, const unsigned short* __restrict__ Tcd,
                               const float* __restrict__ bx, unsigned short* __restrict__ xg,
                               float* __restrict__ corrf) {
  const int r0 = blockIdx.x * 32;
  const int c8 = (threadIdx.x & 15) * 8;
  const float4 bx0 = *(const float4*)(bx + c8);
  const float4 bx1 = *(const float4*)(bx + c8 + 4);
  float bb[8] = {bx0.x, bx0.y, bx0.z, bx0.w, bx1.x, bx1.y, bx1.z, bx1.w};
  union U8 { uint4 v; unsigned short s[8]; };
#pragma unroll
  for (int half = 0; half < 2; ++half) {
    const int r = r0 + (threadIdx.x >> 4) + half * 16;
    const int s = r >> 10, b = r & 1023;
    const int q = qs[b * S_LEN + s], c = cs[b * S_LEN + s];
    const int qd = qds[b * S_LEN + s], cd = cds[b * S_LEN + s];
    U8 vq, vc, vd, ve, o;
    vq.v = *(const uint4*)(Tq + (size_t)q * DIM + c8);
    vc.v = *(const uint4*)(Tc + (size_t)c * DIM + c8);
    vd.v = *(const uint4*)(Tqd + (size_t)qd * DIM + c8);
    ve.v = *(const uint4*)(Tcd + (size_t)cd * DIM + c8);
#pragma unroll
    for (int j = 0; j < 8; ++j)
      o.s[j] = f2b(b2f(vq.s[j]) + b2f(vc.s[j]) + b2f(vd.s[j]) + b2f(ve.s[j]) + bb[j]);
    *(uint4*)(xg + (size_t)r * DIM + c8) = o.v;
    if ((threadIdx.x & 15) == 0) corrf[r] = (float)corr[b * S_LEN + s];
  }
}

// ---------------- P3: GG[r][:] = x[r]@Wkh.T + Tkc[ci] + Tkqd[qi] + Tkcd[di]
__global__ void gemm_xg_kernel(const unsigned short* __restrict__ xg,
                               const float* __restrict__ Wk,
                               const int* __restrict__ corr, const int* __restrict__ qds,
                               const int* __restrict__ cds,
                               const float* __restrict__ Tkc,
                               const unsigned short* __restrict__ Tkqd,
                               const unsigned short* __restrict__ Tkcd,
                               unsigned short* __restrict__ GG) {
  const int tid = threadIdx.x;
  const int r0 = blockIdx.x * 128;   // r = t*1024 + b, t <= 198
  __shared__ __align__(16) unsigned short TS[128][136];
#pragma unroll
  for (int it = 0; it < 2; ++it) {
    const int idx = tid + 256 * it;
    const int row = idx >> 2, cb = (idx & 3) * 32;
    const int r = r0 + row, t = r >> 10, b = r & 1023;
    const int ci = corr[b * S_LEN + t], qi = qds[b * S_LEN + t], di = cds[b * S_LEN + t];
    union U8 { uint4 v; unsigned short s[8]; };
#pragma unroll
    for (int cc = 0; cc < 4; ++cc) {
      const int c8 = cb + cc * 8;
      U8 vq, vc, o;
      vq.v = *(const uint4*)(Tkqd + (size_t)qi * DIM + c8);
      vc.v = *(const uint4*)(Tkcd + (size_t)di * DIM + c8);
      const float4 k0 = *(const float4*)(Tkc + (size_t)ci * DIM + c8);
      const float4 k1 = *(const float4*)(Tkc + (size_t)ci * DIM + c8 + 4);
      float kk[8] = {k0.x, k0.y, k0.z, k0.w, k1.x, k1.y, k1.z, k1.w};
#pragma unroll
      for (int j = 0; j < 8; ++j) o.s[j] = f2b(kk[j] + b2f(vq.s[j]) + b2f(vc.s[j]));
      *(uint4*)&TS[row][c8] = o.v;
    }
  }
  __syncthreads();
  const int w = tid >> 6, L = tid & 63, q = L >> 4, m = L & 15;
  short8 wk[2][4];
#pragma unroll
  for (int T = 0; T < 2; ++T) {
    const int n = 32 * w + 16 * T + m;
#pragma unroll
    for (int kb = 0; kb < 4; ++kb) {
      const float* src = Wk + (size_t)n * 512 + kb * 32 + q * 8;
      const float4 v0 = *(const float4*)src;
      const float4 v1 = *(const float4*)(src + 4);
      short8 f;
      f[0] = (short)f2b(v0.x); f[1] = (short)f2b(v0.y);
      f[2] = (short)f2b(v0.z); f[3] = (short)f2b(v0.w);
      f[4] = (short)f2b(v1.x); f[5] = (short)f2b(v1.y);
      f[6] = (short)f2b(v1.z); f[7] = (short)f2b(v1.w);
      wk[T][kb] = f;
    }
  }
  const f32x4 vzero = {0.f, 0.f, 0.f, 0.f};
#pragma unroll
  for (int mt = 0; mt < 8; ++mt) {
    short8 af[4];
#pragma unroll
    for (int kb = 0; kb < 4; ++kb)
      af[kb] = *(const short8*)(xg + (size_t)(r0 + mt * 16 + m) * DIM + kb * 32 + q * 8);
    f32x4 acc[2] = {vzero, vzero};
#pragma unroll
    for (int kb = 0; kb < 4; ++kb) {
#pragma unroll
      for (int T = 0; T < 2; ++T)
        acc[T] = __builtin_amdgcn_mfma_f32_16x16x32_bf16(af[kb], wk[T][kb], acc[T], 0, 0, 0);
    }
#pragma unroll
    for (int T = 0; T < 2; ++T) {
      const int col = 32 * w + 16 * T + m;
#pragma unroll
      for (int i = 0; i < 4; ++i) {
        const int row128 = mt * 16 + q * 4 + i;
        GG[(size_t)(r0 + row128) * DIM + col] = f2b(acc[T][i] + b2f(TS[row128][col]));
      }
    }
  }
}

// ---------------- P4: recurrence. 64 blocks x 1024 thr (16 waves; pair (w,w+8)
// shares cols 16*(w&7).. and splits the 4 acc rows: hb=0 rows {0,1}, hb=2 {2,3}).
#define SEL(V, i) (hb ? (V)[2 + (i)] : (V)[(i)])
__global__ __launch_bounds__(1024, 4) void scan_kernel(
    const unsigned short* __restrict__ xg,    // [S][B][D] bf16
    const unsigned short* __restrict__ gg,    // [S-1][B][D] bf16
    const float* __restrict__ corrf,          // [S][B] fp32 (0.0/1.0)
    const float* __restrict__ h0,
    const float* __restrict__ Ws1, const float* __restrict__ bs1,
    const float* __restrict__ Ws2, const float* __restrict__ bs2,
    const float* __restrict__ Wp1, const float* __restrict__ Wp2,
    const float* __restrict__ Wk,
    const float* __restrict__ gTp1c, const float* __restrict__ gTp2c,
    float* __restrict__ outp) {
  __shared__ __align__(16) unsigned short Sbuf[16][136];
  __shared__ __align__(16) unsigned short Pbuf[16][136];
  __shared__ __align__(16) unsigned short Wp1L[128][136];  // Wp1[:, :128] bf16
  __shared__ __align__(16) unsigned short Wp2L[128][136];
  __shared__ float DotBuf[16][9];

  const int tid = threadIdx.x;
  const int w16 = tid >> 6;          // 0..15
  const int wc = w16 & 7;            // col-group
  const int hb = (w16 >> 3) << 1;    // 0 or 2: which acc-row half this wave owns
  const int L = tid & 63, q = L >> 4, m = L & 15;
  const int col16 = 16 * wc + m;
  const int rbase = blockIdx.x << 4;
  const size_t SB = (size_t)NBATCH * DIM;

  // stage Wp1s/Wp2s into LDS (fp32 -> bf16): thread handles 16 cols of one row
  {
    const int n = tid >> 3;
    const int c0 = (tid & 7) * 16;
    const float* s1 = Wp1 + (size_t)n * 256 + c0;
    const float* s2 = Wp2 + (size_t)n * 256 + c0;
    union U8 { uint4 v; unsigned short s[8]; } o;
#pragma unroll
    for (int hh = 0; hh < 2; ++hh) {
      float4 a = *(const float4*)(s1 + hh * 8);
      float4 b = *(const float4*)(s1 + hh * 8 + 4);
      o.s[0] = f2b(a.x); o.s[1] = f2b(a.y); o.s[2] = f2b(a.z); o.s[3] = f2b(a.w);
      o.s[4] = f2b(b.x); o.s[5] = f2b(b.y); o.s[6] = f2b(b.z); o.s[7] = f2b(b.w);
      *(uint4*)&Wp1L[n][c0 + hh * 8] = o.v;
      a = *(const float4*)(s2 + hh * 8);
      b = *(const float4*)(s2 + hh * 8 + 4);
      o.s[0] = f2b(a.x); o.s[1] = f2b(a.y); o.s[2] = f2b(a.z); o.s[3] = f2b(a.w);
      o.s[4] = f2b(b.x); o.s[5] = f2b(b.y); o.s[6] = f2b(b.z); o.s[7] = f2b(b.w);
      *(uint4*)&Wp2L[n][c0 + hh * 8] = o.v;
    }
  }

  // register B-fragments: Ws1, Ws2, Wkh
  short8 wf[3][4];
  {
    const float* Wptr[3] = {Ws1, Ws2, Wk};
    const int ldw[3] = {128, 128, 512};
#pragma unroll
    for (int M = 0; M < 3; ++M) {
#pragma unroll
      for (int kb = 0; kb < 4; ++kb) {
        const float* src = Wptr[M] + (size_t)col16 * ldw[M] + kb * 32 + q * 8;
        const float4 v0 = *(const float4*)src;
        const float4 v1 = *(const float4*)(src + 4);
        short8 f;
        f[0] = (short)f2b(v0.x); f[1] = (short)f2b(v0.y);
        f[2] = (short)f2b(v0.z); f[3] = (short)f2b(v0.w);
        f[4] = (short)f2b(v1.x); f[5] = (short)f2b(v1.y);
        f[6] = (short)f2b(v1.z); f[7] = (short)f2b(v1.w);
        wf[M][kb] = f;
      }
    }
  }
  const float bs1v = bs1[col16], bs2v = bs2[col16];
  const float tp1v0 = gTp1c[col16], dtp1 = gTp1c[DIM + col16] - tp1v0;
  const float tp2v0 = gTp2c[col16], dtp2 = gTp2c[DIM + col16] - tp2v0;

  // init h (2 rows per lane), Sbuf = x[0]-h0
  float h[2];
#pragma unroll
  for (int i = 0; i < 2; ++i) {
    const int row = q * 4 + hb + i;
    const int b = rbase + row;
    const float hv = h0[(size_t)b * DIM + col16];
    h[i] = hv;
    const float xt = b2f(xg[(size_t)b * DIM + col16]);
    Sbuf[row][col16] = f2b(xt - hv);
  }
  if (tid < 16) outp[(size_t)(rbase + tid) * S_LEN + (S_LEN - 1)] = 0.0f;

  // distance-1 pointer-walk streams (x[t+1], gg[t], corrf[t]) for our 2 rows
  unsigned short XP[2], GP[2];
  float2 CF;
  const unsigned short* px = xg + 2 * SB + (size_t)(rbase + q * 4 + hb) * DIM + col16;
  const unsigned short* pg = gg + 1 * SB + (size_t)(rbase + q * 4 + hb) * DIM + col16;
  const float* pc = corrf + 1 * NBATCH + rbase + q * 4 + hb;
#pragma unroll
  for (int i = 0; i < 2; ++i) {
    XP[i] = xg[SB + (size_t)(rbase + q * 4 + hb + i) * DIM + col16];  // x[1]
    GP[i] = gg[(size_t)(rbase + q * 4 + hb + i) * DIM + col16];       // gg[0]
  }
  CF = *(const float2*)(corrf + rbase + q * 4 + hb);

  float dotp[2] = {0.f, 0.f};
  const f32x4 vzero = {0.f, 0.f, 0.f, 0.f};

#pragma unroll 1
  for (int t = 0; t < S_LEN - 1; ++t) {
    // consume distance-1 prefetches
    float xnv[2] = {b2f(XP[0]), b2f(XP[1])};
    float ggv[2] = {b2f(GP[0]), b2f(GP[1])};
    const float cf0 = CF.x, cf1 = CF.y;
    // reissue for t+1 (vmcnt stays in flight across lgkm-only barriers)
    XP[0] = px[0]; XP[1] = px[DIM];
    GP[0] = pg[0]; GP[1] = pg[DIM];
    CF = *(const float2*)pc;
    px += SB; pg += SB; pc += NBATCH;

    wg_barrier_lds();  // BAR1: Sbuf(t) ready; orders DotBuf read(t-1) vs write(t)
    short8 sf[4];
#pragma unroll
    for (int kb = 0; kb < 4; ++kb) sf[kb] = *(const short8*)&Sbuf[m][kb * 32 + q * 8];
    // y_{t-1} partial reduce in the sf-read shadow (2 rows, 8 bpermutes)
    {
      float d0 = dotp[0], d1 = dotp[1];
#pragma unroll
      for (int off = 1; off <= 8; off <<= 1) {
        d0 += __shfl_xor(d0, off, 64);
        d1 += __shfl_xor(d1, off, 64);
      }
      if (m == 0) {
        DotBuf[q * 4 + hb + 0][wc] = d0;
        DotBuf[q * 4 + hb + 1][wc] = d1;
      }
    }
    f32x4 a1 = vzero, a2 = vzero, c1 = vzero;
#pragma unroll
    for (int kb = 0; kb < 4; ++kb) {
      a1 = __builtin_amdgcn_mfma_f32_16x16x32_bf16(sf[kb], wf[0][kb], a1, 0, 0, 0);
      a2 = __builtin_amdgcn_mfma_f32_16x16x32_bf16(sf[kb], wf[1][kb], a2, 0, 0, 0);
      c1 = __builtin_amdgcn_mfma_f32_16x16x32_bf16(sf[kb], wf[2][kb], c1, 0, 0, 0);
    }
    {
      const float s0 = sigtanh(SEL(a1, 0) + bs1v, SEL(a2, 0) + bs2v);
      const float s1 = sigtanh(SEL(a1, 1) + bs1v, SEL(a2, 1) + bs2v);
      const unsigned u = pk_bf16(s0, s1);
      Pbuf[q * 4 + hb + 0][col16] = (unsigned short)u;
      Pbuf[q * 4 + hb + 1][col16] = (unsigned short)(u >> 16);
    }
    wg_barrier_lds();  // BAR2: Pbuf + DotBuf ready
    short8 pf[4];
#pragma unroll
    for (int kb = 0; kb < 4; ++kb) pf[kb] = *(const short8*)&Pbuf[m][kb * 32 + q * 8];
    if (t > 0 && tid < 16) {  // y_{t-1} finalize in pf-read shadow
      float d = 0.f;
#pragma unroll
      for (int ww = 0; ww < 8; ++ww) d += DotBuf[tid][ww];
      outp[(size_t)(rbase + tid) * S_LEN + (t - 1)] = fast_sigmoid(d);
    }
    f32x4 p1 = vzero, p2 = vzero;
#pragma unroll
    for (int kb = 0; kb < 4; ++kb) {
      const short8 w1 = *(const short8*)&Wp1L[col16][kb * 32 + q * 8];
      p1 = __builtin_amdgcn_mfma_f32_16x16x32_bf16(pf[kb], w1, p1, 0, 0, 0);
      const short8 w2 = *(const short8*)&Wp2L[col16][kb * 32 + q * 8];
      p2 = __builtin_amdgcn_mfma_f32_16x16x32_bf16(pf[kb], w2, p2, 0, 0, 0);
    }
    float sn[2];
    {
      const float g0 = fast_sigmoid(ggv[0] - SEL(c1, 0));
      const float g1 = fast_sigmoid(ggv[1] - SEL(c1, 1));
      const float pka0 = sigtanh(SEL(p1, 0) + fmaf(cf0, dtp1, tp1v0),
                                 SEL(p2, 0) + fmaf(cf0, dtp2, tp2v0));
      const float pka1 = sigtanh(SEL(p1, 1) + fmaf(cf1, dtp1, tp1v0),
                                 SEL(p2, 1) + fmaf(cf1, dtp2, tp2v0));
      const float hn0 = pka0 + g0 * (h[0] - pka0);
      const float hn1 = pka1 + g1 * (h[1] - pka1);
      h[0] = hn0; h[1] = hn1;
      sn[0] = xnv[0] - hn0; sn[1] = xnv[1] - hn1;
      dotp[0] = xnv[0] * hn0; dotp[1] = xnv[1] * hn1;
    }
    {
      const unsigned u = pk_bf16(sn[0], sn[1]);
      Sbuf[q * 4 + hb + 0][col16] = (unsigned short)u;
      Sbuf[q * 4 + hb + 1][col16] = (unsigned short)(u >> 16);
    }
  }

  // epilogue: y(198)
  {
    float d0 = dotp[0], d1 = dotp[1];
#pragma unroll
    for (int off = 1; off <= 8; off <<= 1) {
      d0 += __shfl_xor(d0, off, 64);
      d1 += __shfl_xor(d1, off, 64);
    }
    if (m == 0) {
      DotBuf[q * 4 + hb + 0][wc] = d0;
      DotBuf[q * 4 + hb + 1][wc] = d1;
    }
  }
  wg_barrier_lds();
  if (tid < 16) {
    float d = 0.f;
#pragma unroll
    for (int ww = 0; ww < 8; ++ww) d += DotBuf[tid][ww];
    outp[(size_t)(rbase + tid) * S_LEN + (S_LEN - 2)] = fast_sigmoid(d);
  }
}

extern "C" void kernel_launch(void* const* d_in, const int* in_sizes, int n_in,
                              void* d_out, int out_size, void* d_ws, size_t ws_size,
                              hipStream_t stream) {
  const int* qs    = (const int*)d_in[0];
  const int* cs    = (const int*)d_in[1];
  const int* qds   = (const int*)d_in[2];
  const int* cds   = (const int*)d_in[3];
  const int* corr  = (const int*)d_in[4];
  const float* Eq    = (const float*)d_in[5];
  const float* Ec    = (const float*)d_in[6];
  const float* Eqd   = (const float*)d_in[7];
  const float* Ecd   = (const float*)d_in[8];
  const float* Ecorr = (const float*)d_in[9];
  const float* Wx  = (const float*)d_in[10];
  const float* bx  = (const float*)d_in[11];
  const float* Ws1 = (const float*)d_in[12];
  const float* bs1 = (const float*)d_in[13];
  const float* Ws2 = (const float*)d_in[14];
  const float* bs2 = (const float*)d_in[15];
  const float* Wp1 = (const float*)d_in[16];
  const float* bp1 = (const float*)d_in[17];
  const float* Wp2 = (const float*)d_in[18];
  const float* bp2 = (const float*)d_in[19];
  const float* Wk  = (const float*)d_in[20];
  const float* bk  = (const float*)d_in[21];
  const float* h0  = (const float*)d_in[22];

  char* ws = (char*)d_ws;
  // layout: X | GG (aliases Tq..Tcd during build) | corrf | small tables.
  // Stream overruns (<=1 slab past X/GG ends) land in the next region --
  // harmless garbage reads inside d_ws, never consumed.
  const size_t xbytes = (size_t)S_LEN * NBATCH * DIM * 2;
  const size_t A = (xbytes + 255) & ~(size_t)255;
  const size_t ggbytes = (size_t)(S_LEN - 1) * NBATCH * DIM * 2;
  unsigned short* X  = (unsigned short*)ws;
  unsigned short* GG = (unsigned short*)(ws + A);
  unsigned short* Tq  = GG;  // alias (dead after build_x)
  unsigned short* Tc  = (unsigned short*)(ws + A + (size_t)50000 * DIM * 2);
  unsigned short* Tqd = (unsigned short*)(ws + A + (size_t)51000 * DIM * 2);
  unsigned short* Tcd = (unsigned short*)(ws + A + (size_t)51101 * DIM * 2);
  size_t off = A + ((ggbytes + 255) & ~(size_t)255);
  auto alloc = [&](size_t bytes) {
    void* p = ws + off;
    off = (off + bytes + 255) & ~(size_t)255;
    return p;
  };
  float* corrf = (float*)alloc((size_t)S_LEN * NBATCH * 4);
  unsigned short* Tkqd = (unsigned short*)alloc((size_t)101 * DIM * 2);
  unsigned short* Tkcd = (unsigned short*)alloc((size_t)101 * DIM * 2);
  float* Tkc  = (float*)alloc((size_t)2 * DIM * 4);
  float* Tp1c = (float*)alloc((size_t)2 * DIM * 4);
  float* Tp2c = (float*)alloc((size_t)2 * DIM * 4);

  proj_all_kernel<<<904, 256, 0, stream>>>(Eq, Ec, Eqd, Ecd, Ecorr, Wx,
                                           Wp1, bp1, Wp2, bp2, Wk, bk,
                                           Tq, Tc, Tqd, Tcd, Tkqd, Tkcd, Tkc, Tp1c, Tp2c);
  build_x_kernel<<<(S_LEN * NBATCH) / 32, 256, 0, stream>>>(qs, cs, qds, cds, corr,
                                                            Tq, Tc, Tqd, Tcd, bx, X, corrf);
  // Tq..Tcd dead now -> GG overwrites them
  gemm_xg_kernel<<<((S_LEN - 1) * NBATCH) / 128, 256, 0, stream>>>(X, Wk, corr, qds, cds,
                                                                   Tkc, Tkqd, Tkcd, GG);
  scan_kernel<<<64, 1024, 0, stream>>>(X, GG, corrf, h0, Ws1, bs1, Ws2, bs2,
                                       Wp1, Wp2, Wk, Tp1c, Tp2c, (float*)d_out);
}

// Round 9
// 514.207 us; speedup vs baseline: 1.2783x; 1.2783x over previous
//
#include <hip/hip_runtime.h>
#include <hip/hip_bf16.h>

// DIMKT: B=1024, S=200, D=128.
// R9: R6 scan structure (best measured: 293us) + trans-pipe diet only:
// phase A sigtanh (3 trans), phase B merged single-rcp gate+pka (4 trans).
// Prep: build_x + gemm_xg fused into build_xg (X staged in LDS, one pass).

#define S_LEN 200
#define NBATCH 1024
#define DIM 128
#define LOG2E 1.4426950408889634f

typedef short short8 __attribute__((ext_vector_type(8)));
typedef float f32x4 __attribute__((ext_vector_type(4)));

__device__ __forceinline__ unsigned short f2b(float f) {
  union { float f; unsigned u; } v; v.f = f;
  unsigned r = (v.u + 0x7FFFu + ((v.u >> 16) & 1u)) >> 16;  // RNE
  return (unsigned short)r;
}
__device__ __forceinline__ float b2f(unsigned short b) {
  union { unsigned u; float f; } v; v.u = ((unsigned)b) << 16;
  return v.f;
}
__device__ __forceinline__ unsigned pk_bf16(float lo, float hi) {
  __hip_bfloat162 t = __float22bfloat162_rn(make_float2(lo, hi));
  union { __hip_bfloat162 h; unsigned u; } cv; cv.h = t;
  return cv.u;
}
// sig(a)*tanh(b): 3 trans, clamps prevent overflow (u,v <= 2^43 -> den <= 2^87)
__device__ __forceinline__ float sigtanh(float a, float b) {
  a = fminf(a, 30.0f);
  b = fminf(b, 15.0f);
  const float u = __builtin_amdgcn_exp2f(LOG2E * a);
  const float v = __builtin_amdgcn_exp2f(2.0f * LOG2E * b);
  return (u * (v - 1.0f)) * __builtin_amdgcn_rcpf((1.0f + u) * (v + 1.0f));
}
__device__ __forceinline__ float fast_sigmoid(float x) {
  x = fmaxf(x, -30.0f);
  return __builtin_amdgcn_rcpf(1.0f + __builtin_amdgcn_exp2f(-LOG2E * x));
}
// LDS-only barrier: does NOT drain vmcnt, prefetches stay in flight.
__device__ __forceinline__ void wg_barrier_lds() {
  __asm__ volatile("s_waitcnt lgkmcnt(0)\n\ts_barrier" ::: "memory");
}

// ---------------- P1: projected embedding tables via MFMA, 64 rows/block.
// blocks: [0,782) Tq | [782,798) Tc | [798,800) Tqd | [800,802) Tcd | [802,904) small
__global__ void proj_all_kernel(const float* __restrict__ Eq, const float* __restrict__ Ec,
                                const float* __restrict__ Eqd, const float* __restrict__ Ecd,
                                const float* __restrict__ Ecorr,
                                const float* __restrict__ Wx,
                                const float* __restrict__ Wp1, const float* __restrict__ bp1,
                                const float* __restrict__ Wp2, const float* __restrict__ bp2,
                                const float* __restrict__ Wk, const float* __restrict__ bk,
                                unsigned short* __restrict__ Tq, unsigned short* __restrict__ Tc,
                                unsigned short* __restrict__ Tqd, unsigned short* __restrict__ Tcd,
                                unsigned short* __restrict__ Tkqd, unsigned short* __restrict__ Tkcd,
                                float* __restrict__ Tkc, float* __restrict__ Tp1c,
                                float* __restrict__ Tp2c) {
  const int bid = blockIdx.x;
  const int tid = threadIdx.x;
  if (bid >= 802) {
    const int blk = bid - 802;
    if (blk < 101) {
      const int o = tid & 127, half = tid >> 7;
      const float* e = (half ? Ecd : Eqd) + (size_t)blk * DIM;
      const float* wr = Wk + (size_t)o * 512 + (half ? 384 : 256);
      float a = 0.f;
      for (int k = 0; k < DIM; ++k) a = fmaf(e[k], wr[k], a);
      (half ? Tkcd : Tkqd)[blk * DIM + o] = f2b(a);
    } else {
      for (int idx = tid; idx < 768; idx += 256) {
        const int t = idx >> 8, e = (idx >> 7) & 1, o = idx & 127;
        const float* ec = Ecorr + e * DIM;
        const float* wr; float bias; float* dst;
        if (t == 0)      { wr = Wp1 + (size_t)o * 256 + 128; bias = bp1[o]; dst = Tp1c; }
        else if (t == 1) { wr = Wp2 + (size_t)o * 256 + 128; bias = bp2[o]; dst = Tp2c; }
        else             { wr = Wk  + (size_t)o * 512 + 128; bias = bk[o];  dst = Tkc;  }
        float a = bias;
        for (int k = 0; k < DIM; ++k) a = fmaf(ec[k], wr[k], a);
        dst[e * DIM + o] = a;
      }
    }
    return;
  }
  const float* E; int M, coff, r0; unsigned short* T;
  if (bid < 782)      { E = Eq;  M = 50000; coff = 0;   T = Tq;  r0 = bid * 64; }
  else if (bid < 798) { E = Ec;  M = 1000;  coff = 128; T = Tc;  r0 = (bid - 782) * 64; }
  else if (bid < 800) { E = Eqd; M = 101;   coff = 256; T = Tqd; r0 = (bid - 798) * 64; }
  else                { E = Ecd; M = 101;   coff = 384; T = Tcd; r0 = (bid - 800) * 64; }

  __shared__ __align__(16) unsigned short A[64][136];
  {
    const int row = tid >> 2, cb = (tid & 3) * 32;
    union U8 { uint4 v; unsigned short s[8]; } o;
#pragma unroll
    for (int cc = 0; cc < 4; ++cc) {
      const int c8 = cb + cc * 8;
      if (r0 + row < M) {
        const float4 e0 = *(const float4*)(E + (size_t)(r0 + row) * DIM + c8);
        const float4 e1 = *(const float4*)(E + (size_t)(r0 + row) * DIM + c8 + 4);
        o.s[0] = f2b(e0.x); o.s[1] = f2b(e0.y); o.s[2] = f2b(e0.z); o.s[3] = f2b(e0.w);
        o.s[4] = f2b(e1.x); o.s[5] = f2b(e1.y); o.s[6] = f2b(e1.z); o.s[7] = f2b(e1.w);
      } else {
        o.v = make_uint4(0, 0, 0, 0);
      }
      *(uint4*)&A[row][c8] = o.v;
    }
  }
  __syncthreads();
  const int w = tid >> 6, L = tid & 63, q = L >> 4, m = L & 15;
  short8 bf[2][4];
#pragma unroll
  for (int T2 = 0; T2 < 2; ++T2) {
    const int n = 32 * w + 16 * T2 + m;
#pragma unroll
    for (int kb = 0; kb < 4; ++kb) {
      const float* src = Wx + (size_t)n * 512 + coff + kb * 32 + q * 8;
      const float4 v0 = *(const float4*)src;
      const float4 v1 = *(const float4*)(src + 4);
      short8 f;
      f[0] = (short)f2b(v0.x); f[1] = (short)f2b(v0.y);
      f[2] = (short)f2b(v0.z); f[3] = (short)f2b(v0.w);
      f[4] = (short)f2b(v1.x); f[5] = (short)f2b(v1.y);
      f[6] = (short)f2b(v1.z); f[7] = (short)f2b(v1.w);
      bf[T2][kb] = f;
    }
  }
  const f32x4 vzero = {0.f, 0.f, 0.f, 0.f};
#pragma unroll
  for (int mt = 0; mt < 4; ++mt) {
    short8 af[4];
#pragma unroll
    for (int kb = 0; kb < 4; ++kb) af[kb] = *(const short8*)&A[mt * 16 + m][kb * 32 + q * 8];
    f32x4 acc[2] = {vzero, vzero};
#pragma unroll
    for (int kb = 0; kb < 4; ++kb) {
#pragma unroll
      for (int T2 = 0; T2 < 2; ++T2)
        acc[T2] = __builtin_amdgcn_mfma_f32_16x16x32_bf16(af[kb], bf[T2][kb], acc[T2], 0, 0, 0);
    }
#pragma unroll
    for (int T2 = 0; T2 < 2; ++T2) {
      const int col = 32 * w + 16 * T2 + m;
#pragma unroll
      for (int i = 0; i < 4; ++i) {
        const int r = r0 + mt * 16 + q * 4 + i;
        if (r < M) T[(size_t)r * DIM + col] = f2b(acc[T2][i]);
      }
    }
  }
}

// ---------------- P2 (fused): per 128-row tile (one s-slab slice):
//   x = Tq+Tc+Tqd+Tcd+bx -> LDS + global X; SS = sum(x^2); corrf;
//   TS = Tkc[ci]+Tkqd[qi]+Tkcd[di] -> LDS;
//   GG = x@Wkh.T + TS  (skipped for s==199).
__global__ void build_xg_kernel(const int* __restrict__ qs, const int* __restrict__ cs,
                                const int* __restrict__ qds, const int* __restrict__ cds,
                                const int* __restrict__ corr,
                                const unsigned short* __restrict__ Tq, const unsigned short* __restrict__ Tc,
                                const unsigned short* __restrict__ Tqd, const unsigned short* __restrict__ Tcd,
                                const float* __restrict__ bx,
                                const float* __restrict__ Wk,
                                const float* __restrict__ Tkc,
                                const unsigned short* __restrict__ Tkqd,
                                const unsigned short* __restrict__ Tkcd,
                                unsigned short* __restrict__ xg, float* __restrict__ SSg,
                                float* __restrict__ corrf, unsigned short* __restrict__ GG) {
  __shared__ __align__(16) unsigned short XT[128][136];
  __shared__ __align__(16) unsigned short TSL[128][136];
  const int tid = threadIdx.x;
  const int r0 = blockIdx.x * 128;          // 128 | 1024 -> whole block same s
  const int s = r0 >> 10;
  const int c8 = (tid & 15) * 8;
  const float4 bx0 = *(const float4*)(bx + c8);
  const float4 bx1 = *(const float4*)(bx + c8 + 4);
  float bb[8] = {bx0.x, bx0.y, bx0.z, bx0.w, bx1.x, bx1.y, bx1.z, bx1.w};
  union U8 { uint4 v; unsigned short s[8]; };

  // Wk B-frags for phase 2 (issued early, overlap phase-1 gathers)
  const int w = tid >> 6, L = tid & 63, q = L >> 4, m = L & 15;
  short8 wk[2][4];
#pragma unroll
  for (int T = 0; T < 2; ++T) {
    const int n = 32 * w + 16 * T + m;
#pragma unroll
    for (int kb = 0; kb < 4; ++kb) {
      const float* src = Wk + (size_t)n * 512 + kb * 32 + q * 8;
      const float4 v0 = *(const float4*)src;
      const float4 v1 = *(const float4*)(src + 4);
      short8 f;
      f[0] = (short)f2b(v0.x); f[1] = (short)f2b(v0.y);
      f[2] = (short)f2b(v0.z); f[3] = (short)f2b(v0.w);
      f[4] = (short)f2b(v1.x); f[5] = (short)f2b(v1.y);
      f[6] = (short)f2b(v1.z); f[7] = (short)f2b(v1.w);
      wk[T][kb] = f;
    }
  }

#pragma unroll
  for (int it = 0; it < 8; ++it) {
    const int row = (tid >> 4) + 16 * it;
    const int r = r0 + row;
    const int b = r & 1023;
    const int qi2 = qs[b * S_LEN + s], ci2 = cs[b * S_LEN + s];
    const int qd = qds[b * S_LEN + s], cd = cds[b * S_LEN + s];
    const int cr = corr[b * S_LEN + s];
    U8 vq, vc, vd, ve, o;
    vq.v = *(const uint4*)(Tq + (size_t)qi2 * DIM + c8);
    vc.v = *(const uint4*)(Tc + (size_t)ci2 * DIM + c8);
    vd.v = *(const uint4*)(Tqd + (size_t)qd * DIM + c8);
    ve.v = *(const uint4*)(Tcd + (size_t)cd * DIM + c8);
    float part = 0.f;
#pragma unroll
    for (int j = 0; j < 8; ++j) {
      const float sv = b2f(vq.s[j]) + b2f(vc.s[j]) + b2f(vd.s[j]) + b2f(ve.s[j]) + bb[j];
      o.s[j] = f2b(sv);
      const float xr = b2f(o.s[j]);
      part = fmaf(xr, xr, part);
    }
    *(uint4*)&XT[row][c8] = o.v;
    *(uint4*)(xg + (size_t)r * DIM + c8) = o.v;
    // TS (gate-bias) for this row
    U8 tq2, tc2, ot;
    tq2.v = *(const uint4*)(Tkqd + (size_t)qd * DIM + c8);
    tc2.v = *(const uint4*)(Tkcd + (size_t)cd * DIM + c8);
    const float4 k0 = *(const float4*)(Tkc + (size_t)cr * DIM + c8);
    const float4 k1 = *(const float4*)(Tkc + (size_t)cr * DIM + c8 + 4);
    float kk[8] = {k0.x, k0.y, k0.z, k0.w, k1.x, k1.y, k1.z, k1.w};
#pragma unroll
    for (int j = 0; j < 8; ++j) ot.s[j] = f2b(kk[j] + b2f(tq2.s[j]) + b2f(tc2.s[j]));
    *(uint4*)&TSL[row][c8] = ot.v;
    // SS reduce over the row's 16 threads (aligned 16-lane group)
#pragma unroll
    for (int off = 1; off <= 8; off <<= 1) part += __shfl_xor(part, off, 64);
    if ((tid & 15) == 0) {
      SSg[r] = part;
      corrf[r] = (float)cr;
    }
  }
  __syncthreads();
  if (s == 199) return;   // uniform: no GG for the last slab

  const f32x4 vzero = {0.f, 0.f, 0.f, 0.f};
#pragma unroll
  for (int mt = 0; mt < 8; ++mt) {
    short8 af[4];
#pragma unroll
    for (int kb = 0; kb < 4; ++kb) af[kb] = *(const short8*)&XT[mt * 16 + m][kb * 32 + q * 8];
    f32x4 acc[2] = {vzero, vzero};
#pragma unroll
    for (int kb = 0; kb < 4; ++kb) {
#pragma unroll
      for (int T = 0; T < 2; ++T)
        acc[T] = __builtin_amdgcn_mfma_f32_16x16x32_bf16(af[kb], wk[T][kb], acc[T], 0, 0, 0);
    }
#pragma unroll
    for (int T = 0; T < 2; ++T) {
      const int col = 32 * w + 16 * T + m;
#pragma unroll
      for (int i = 0; i < 4; ++i) {
        const int row128 = mt * 16 + q * 4 + i;
        GG[(size_t)(r0 + row128) * DIM + col] = f2b(acc[T][i] + b2f(TSL[row128][col]));
      }
    }
  }
}

// ---------------- P3: the recurrence. 64 blocks x 512 thr (8 waves x 16 cols).
__global__ __launch_bounds__(512, 2) void scan_kernel(
    const unsigned short* __restrict__ xg,    // [S][B][D] bf16
    const unsigned short* __restrict__ gg,    // [S-1][B][D] bf16 (xWk + tables + bk)
    const float* __restrict__ SSg,            // [S][B] fp32, sum(x^2)
    const float* __restrict__ corrf,          // [S][B] fp32 (0.0/1.0)
    const float* __restrict__ h0,
    const float* __restrict__ Ws1, const float* __restrict__ bs1,
    const float* __restrict__ Ws2, const float* __restrict__ bs2,
    const float* __restrict__ Wp1, const float* __restrict__ Wp2,
    const float* __restrict__ Wk,
    const float* __restrict__ gTp1c, const float* __restrict__ gTp2c,
    float* __restrict__ outp) {
  __shared__ __align__(16) unsigned short Sbuf[16][136];
  __shared__ __align__(16) unsigned short Pbuf[16][136];

  const int tid = threadIdx.x;
  const int w = tid >> 6, L = tid & 63, q = L >> 4, m = L & 15;
  const int col16 = 16 * w + m;
  const int rbase = blockIdx.x << 4;
  const size_t SB = (size_t)NBATCH * DIM;

  short8 wf[5][4];
  {
    const float* Wptr[5] = {Ws1, Ws2, Wp1, Wp2, Wk};
    const int ldw[5] = {128, 128, 256, 256, 512};
#pragma unroll
    for (int M = 0; M < 5; ++M) {
#pragma unroll
      for (int kb = 0; kb < 4; ++kb) {
        const float* src = Wptr[M] + (size_t)col16 * ldw[M] + kb * 32 + q * 8;
        const float4 v0 = *(const float4*)src;
        const float4 v1 = *(const float4*)(src + 4);
        short8 f;
        f[0] = (short)f2b(v0.x); f[1] = (short)f2b(v0.y);
        f[2] = (short)f2b(v0.z); f[3] = (short)f2b(v0.w);
        f[4] = (short)f2b(v1.x); f[5] = (short)f2b(v1.y);
        f[6] = (short)f2b(v1.z); f[7] = (short)f2b(v1.w);
        wf[M][kb] = f;
      }
    }
  }
  const float bs1v = bs1[col16], bs2v = bs2[col16];
  const float tp1v0 = gTp1c[col16], dtp1 = gTp1c[DIM + col16] - tp1v0;
  const float tp2v0 = gTp2c[col16], dtp2 = gTp2c[DIM + col16] - tp2v0;

  float h[4];
#pragma unroll
  for (int i = 0; i < 4; ++i) {
    const int b = rbase + q * 4 + i;
    const float hv = h0[(size_t)b * DIM + col16];
    h[i] = hv;
    const float xt = b2f(xg[(size_t)b * DIM + col16]);
    Sbuf[q * 4 + i][col16] = f2b(xt - hv);
  }
  if (tid < 16) outp[(size_t)(rbase + tid) * S_LEN + (S_LEN - 1)] = 0.0f;
  float* poy = outp + (size_t)(rbase + m) * S_LEN;   // wave0 y stores

  // distance-2 prefetch: register sets A/B + walking pointers (imm offsets)
  unsigned short XPA[4], XPB[4], GPA[4], GPB[4];
  float4 CFA, CFB;
  short8 XFA[4], XFB[4];
  float SSA, SSB;
  const unsigned short* pxA = xg + 3 * SB + (size_t)(rbase + q * 4) * DIM + col16;
  const unsigned short* pxB = pxA + SB;
  const unsigned short* pgA = gg + 2 * SB + (size_t)(rbase + q * 4) * DIM + col16;
  const unsigned short* pgB = pgA + SB;
  const float* pcA = corrf + 2 * NBATCH + rbase + q * 4;
  const float* pcB = pcA + NBATCH;
  const unsigned short* pfA = xg + 2 * SB + (size_t)(rbase + m) * DIM + q * 8;
  const unsigned short* pfB = pfA + SB;
  const float* psA = SSg + 2 * NBATCH + rbase + m;
  const float* psB = psA + NBATCH;
#pragma unroll
  for (int i = 0; i < 4; ++i) {
    XPA[i] = xg[SB + (size_t)(rbase + q * 4 + i) * DIM + col16];      // x[1]
    XPB[i] = xg[2 * SB + (size_t)(rbase + q * 4 + i) * DIM + col16];  // x[2]
    GPA[i] = gg[(size_t)(rbase + q * 4 + i) * DIM + col16];           // gg[0]
    GPB[i] = gg[SB + (size_t)(rbase + q * 4 + i) * DIM + col16];      // gg[1]
  }
  CFA = *(const float4*)(corrf + rbase + q * 4);
  CFB = *(const float4*)(corrf + NBATCH + rbase + q * 4);
#pragma unroll
  for (int kb = 0; kb < 4; ++kb) {
    XFA[kb] = *(const short8*)(xg + (size_t)(rbase + m) * DIM + kb * 32 + q * 8);        // x[0]
    XFB[kb] = *(const short8*)(xg + SB + (size_t)(rbase + m) * DIM + kb * 32 + q * 8);   // x[1]
  }
  SSA = SSg[rbase + m];
  SSB = SSg[NBATCH + rbase + m];

  const f32x4 vzero = {0.f, 0.f, 0.f, 0.f};

#define STEP(TCUR, XP, GP, CF, PX, PG, PC, XF, SSR, PF, PS)                    \
  do {                                                                         \
    const int t_ = (TCUR);                                                     \
    float xnv[4], ggv[4], cfv[4];                                              \
    _Pragma("unroll") for (int i = 0; i < 4; ++i) {                            \
      xnv[i] = b2f(XP[i]); ggv[i] = b2f(GP[i]);                                \
    }                                                                          \
    cfv[0] = CF.x; cfv[1] = CF.y; cfv[2] = CF.z; cfv[3] = CF.w;                \
    short8 xfr[4]; float ssv = SSR;                                            \
    if (w == 0) {                                                              \
      _Pragma("unroll") for (int kb = 0; kb < 4; ++kb) xfr[kb] = XF[kb];       \
    }                                                                          \
    _Pragma("unroll") for (int i = 0; i < 4; ++i) {                            \
      XP[i] = PX[i * DIM]; GP[i] = PG[i * DIM];                                \
    }                                                                          \
    CF = *(const float4*)PC;                                                   \
    PX += 2 * SB; PG += 2 * SB; PC += 2 * NBATCH;                              \
    if (w == 0) {                                                              \
      _Pragma("unroll") for (int kb = 0; kb < 4; ++kb)                         \
        XF[kb] = *(const short8*)(PF + kb * 32);                               \
      SSR = *PS;                                                               \
      PF += 2 * SB; PS += 2 * NBATCH;                                          \
    }                                                                          \
    wg_barrier_lds(); /* Sbuf(t) ready */                                      \
    short8 sf[4];                                                              \
    _Pragma("unroll") for (int kb = 0; kb < 4; ++kb)                           \
        sf[kb] = *(const short8*)&Sbuf[m][kb * 32 + q * 8];                    \
    f32x4 a1 = vzero, a2 = vzero, c1 = vzero;                                  \
    _Pragma("unroll") for (int kb = 0; kb < 4; ++kb) {                         \
      a1 = __builtin_amdgcn_mfma_f32_16x16x32_bf16(sf[kb], wf[0][kb], a1, 0, 0, 0); \
      a2 = __builtin_amdgcn_mfma_f32_16x16x32_bf16(sf[kb], wf[1][kb], a2, 0, 0, 0); \
      c1 = __builtin_amdgcn_mfma_f32_16x16x32_bf16(sf[kb], wf[4][kb], c1, 0, 0, 0); \
    }                                                                          \
    if (w == 0) {                                                              \
      f32x4 dt = vzero;                                                        \
      _Pragma("unroll") for (int kb = 0; kb < 4; ++kb)                         \
        dt = __builtin_amdgcn_mfma_f32_16x16x32_bf16(sf[kb], xfr[kb], dt, 0, 0, 0); \
      if (t_ > 0 && q == (m >> 2)) {                                           \
        const int ii = m & 3;                                                  \
        const float D = ii == 0 ? dt[0] : ii == 1 ? dt[1] : ii == 2 ? dt[2] : dt[3]; \
        poy[t_ - 1] = fast_sigmoid(ssv - D);                                   \
      }                                                                        \
    }                                                                          \
    _Pragma("unroll") for (int i2 = 0; i2 < 2; ++i2) {                         \
      const float s0 = sigtanh(a1[2 * i2] + bs1v, a2[2 * i2] + bs2v);          \
      const float s1 = sigtanh(a1[2 * i2 + 1] + bs1v, a2[2 * i2 + 1] + bs2v);  \
      const unsigned u = pk_bf16(s0, s1);                                      \
      Pbuf[q * 4 + 2 * i2][col16] = (unsigned short)u;                         \
      Pbuf[q * 4 + 2 * i2 + 1][col16] = (unsigned short)(u >> 16);             \
    }                                                                          \
    wg_barrier_lds(); /* Pbuf ready */                                         \
    short8 pf[4];                                                              \
    _Pragma("unroll") for (int kb = 0; kb < 4; ++kb)                           \
        pf[kb] = *(const short8*)&Pbuf[m][kb * 32 + q * 8];                    \
    f32x4 p1 = vzero, p2 = vzero;                                              \
    _Pragma("unroll") for (int kb = 0; kb < 4; ++kb) {                         \
      p1 = __builtin_amdgcn_mfma_f32_16x16x32_bf16(pf[kb], wf[2][kb], p1, 0, 0, 0); \
      p2 = __builtin_amdgcn_mfma_f32_16x16x32_bf16(pf[kb], wf[3][kb], p2, 0, 0, 0); \
    }                                                                          \
    float sn[4];                                                               \
    _Pragma("unroll") for (int i = 0; i < 4; ++i) {                            \
      /* merged gate+pka: one rcp. g=1/(1+A), pka=N/Dd */                      \
      const float e1 = fmaxf(ggv[i] - c1[i], -20.0f);                          \
      const float Aa = __builtin_amdgcn_exp2f(-LOG2E * e1);                    \
      const float ap = fminf(p1[i] + fmaf(cfv[i], dtp1, tp1v0), 20.0f);        \
      const float bp = fminf(p2[i] + fmaf(cfv[i], dtp2, tp2v0), 10.0f);        \
      const float uu = __builtin_amdgcn_exp2f(LOG2E * ap);                     \
      const float vv = __builtin_amdgcn_exp2f(2.0f * LOG2E * bp);              \
      const float Nn = uu * (vv - 1.0f);                                       \
      const float Dd = (1.0f + uu) * (vv + 1.0f);                              \
      const float hn = (h[i] * Dd + Aa * Nn) *                                 \
                       __builtin_amdgcn_rcpf((1.0f + Aa) * Dd);                \
      h[i] = hn;                                                               \
      sn[i] = xnv[i] - hn;                                                     \
    }                                                                          \
    _Pragma("unroll") for (int i2 = 0; i2 < 2; ++i2) {                         \
      const unsigned u = pk_bf16(sn[2 * i2], sn[2 * i2 + 1]);                  \
      Sbuf[q * 4 + 2 * i2][col16] = (unsigned short)u;                         \
      Sbuf[q * 4 + 2 * i2 + 1][col16] = (unsigned short)(u >> 16);             \
    }                                                                          \
  } while (0)

  for (int t2 = 0; t2 < 198; t2 += 2) {
    STEP(t2, XPA, GPA, CFA, pxA, pgA, pcA, XFA, SSA, pfA, psA);
    STEP(t2 + 1, XPB, GPB, CFB, pxB, pgB, pcB, XFB, SSB, pfB, psB);
  }
  STEP(198, XPA, GPA, CFA, pxA, pgA, pcA, XFA, SSA, pfA, psA);
#undef STEP

  // epilogue: y(198) from s(199) in Sbuf, x[199] (= XFB), ss[199] (= SSB)
  wg_barrier_lds();
  if (w == 0) {
    short8 sf[4];
#pragma unroll
    for (int kb = 0; kb < 4; ++kb) sf[kb] = *(const short8*)&Sbuf[m][kb * 32 + q * 8];
    f32x4 dt = vzero;
#pragma unroll
    for (int kb = 0; kb < 4; ++kb)
      dt = __builtin_amdgcn_mfma_f32_16x16x32_bf16(sf[kb], XFB[kb], dt, 0, 0, 0);
    if (q == (m >> 2)) {
      const int ii = m & 3;
      const float D = ii == 0 ? dt[0] : ii == 1 ? dt[1] : ii == 2 ? dt[2] : dt[3];
      poy[S_LEN - 2] = fast_sigmoid(SSB - D);
    }
  }
}

extern "C" void kernel_launch(void* const* d_in, const int* in_sizes, int n_in,
                              void* d_out, int out_size, void* d_ws, size_t ws_size,
                              hipStream_t stream) {
  const int* qs    = (const int*)d_in[0];
  const int* cs    = (const int*)d_in[1];
  const int* qds   = (const int*)d_in[2];
  const int* cds   = (const int*)d_in[3];
  const int* corr  = (const int*)d_in[4];
  const float* Eq    = (const float*)d_in[5];
  const float* Ec    = (const float*)d_in[6];
  const float* Eqd   = (const float*)d_in[7];
  const float* Ecd   = (const float*)d_in[8];
  const float* Ecorr = (const float*)d_in[9];
  const float* Wx  = (const float*)d_in[10];
  const float* bx  = (const float*)d_in[11];
  const float* Ws1 = (const float*)d_in[12];
  const float* bs1 = (const float*)d_in[13];
  const float* Ws2 = (const float*)d_in[14];
  const float* bs2 = (const float*)d_in[15];
  const float* Wp1 = (const float*)d_in[16];
  const float* bp1 = (const float*)d_in[17];
  const float* Wp2 = (const float*)d_in[18];
  const float* bp2 = (const float*)d_in[19];
  const float* Wk  = (const float*)d_in[20];
  const float* bk  = (const float*)d_in[21];
  const float* h0  = (const float*)d_in[22];

  char* ws = (char*)d_ws;
  // layout (NO aliasing now -- build_xg reads tables while writing GG):
  //   X | Tq Tc Tqd Tcd | GG | corrf SS small-tables   (~120 MB total)
  // Scan stream overruns (<=2 slabs past X/GG/corrf/SS ends) stay inside
  // d_ws regions -- harmless garbage reads, never consumed.
  size_t off = 0;
  auto alloc = [&](size_t bytes) {
    void* p = ws + off;
    off = (off + bytes + 255) & ~(size_t)255;
    return p;
  };
  unsigned short* X    = (unsigned short*)alloc((size_t)S_LEN * NBATCH * DIM * 2);
  unsigned short* Tq   = (unsigned short*)alloc((size_t)50000 * DIM * 2);
  unsigned short* Tc   = (unsigned short*)alloc((size_t)1000 * DIM * 2);
  unsigned short* Tqd  = (unsigned short*)alloc((size_t)101 * DIM * 2);
  unsigned short* Tcd  = (unsigned short*)alloc((size_t)101 * DIM * 2);
  unsigned short* GG   = (unsigned short*)alloc((size_t)(S_LEN - 1) * NBATCH * DIM * 2);
  float* corrf = (float*)alloc((size_t)S_LEN * NBATCH * 4);
  float* SS    = (float*)alloc((size_t)S_LEN * NBATCH * 4);
  unsigned short* Tkqd = (unsigned short*)alloc((size_t)101 * DIM * 2);
  unsigned short* Tkcd = (unsigned short*)alloc((size_t)101 * DIM * 2);
  float* Tkc  = (float*)alloc((size_t)2 * DIM * 4);
  float* Tp1c = (float*)alloc((size_t)2 * DIM * 4);
  float* Tp2c = (float*)alloc((size_t)2 * DIM * 4);

  proj_all_kernel<<<904, 256, 0, stream>>>(Eq, Ec, Eqd, Ecd, Ecorr, Wx,
                                           Wp1, bp1, Wp2, bp2, Wk, bk,
                                           Tq, Tc, Tqd, Tcd, Tkqd, Tkcd, Tkc, Tp1c, Tp2c);
  build_xg_kernel<<<(S_LEN * NBATCH) / 128, 256, 0, stream>>>(qs, cs, qds, cds, corr,
                                                              Tq, Tc, Tqd, Tcd, bx, Wk,
                                                              Tkc, Tkqd, Tkcd,
                                                              X, SS, corrf, GG);
  scan_kernel<<<64, 512, 0, stream>>>(X, GG, SS, corrf, h0, Ws1, bs1, Ws2, bs2,
                                      Wp1, Wp2, Wk, Tp1c, Tp2c, (float*)d_out);
}